// Round 4
// baseline (381.636 us; speedup 1.0000x reference)
//
#include <hip/hip_runtime.h>
#include <cstdint>

// ---------------------------------------------------------------------------
// SCAM v4: v3 algebra (folded M = lam*Wq^T@Wk, LN in epilogues) with all LDS
// tiles stored as separate hi/lo bf16 PLANES:
//   - row-fragment reads  -> ds_read_b128 (zero extract VALU)
//   - column walks        -> ds_read_u16 + imm offsets (zero extract VALU)
//   - XOR swizzle idx^=(row&56) on X and E planes (write & read identical)
//     spreads the 8-row-stride column walks across banks.
// Phases: load -> LN stats -> G1 (T2=LN1(xl)@MB) -> G2 (S2=T2@xh^T -> E)
//         -> PV (O_h=(E@Xh)zr, O_l=(E^T@Xl)zc) -> P7 (out = res + Wv@O^T)
// ---------------------------------------------------------------------------

typedef __attribute__((ext_vector_type(8))) short bf16x8;
typedef __attribute__((ext_vector_type(4))) float f32x4;
typedef __attribute__((ext_vector_type(4))) unsigned short u16x4;

#define LAM 0.18033688011112042f  // log2(e)/8

// swizzled u16 index into a pitch-136 plane: (row*136+col) ^ (row&56)
__device__ __forceinline__ int XSW(int r, int c) { return (r * 136 + c) ^ (r & 56); }

__device__ __forceinline__ unsigned rne_hi(float x) {
  unsigned u = __float_as_uint(x);
  return (u + 0x7FFFu + ((u >> 16) & 1u)) >> 16;
}
__device__ __forceinline__ void split2(float x, unsigned short& h, unsigned short& l) {
  unsigned hb = rne_hi(x);
  float rf = x - __uint_as_float(hb << 16);
  h = (unsigned short)hb;
  l = (unsigned short)(__float_as_uint(rf) >> 16);
}
__device__ __forceinline__ float comb(unsigned short h, unsigned short l) {
  return __uint_as_float((unsigned)h << 16) + __uint_as_float((unsigned)l << 16);
}
__device__ __forceinline__ f32x4 mm3(bf16x8 ah, bf16x8 al, bf16x8 bh, bf16x8 bl, f32x4 c) {
  c = __builtin_amdgcn_mfma_f32_16x16x32_bf16(al, bh, c, 0, 0, 0);
  c = __builtin_amdgcn_mfma_f32_16x16x32_bf16(ah, bl, c, 0, 0, 0);
  c = __builtin_amdgcn_mfma_f32_16x16x32_bf16(ah, bh, c, 0, 0, 0);
  return c;
}

// ---------------- prepack (identical to v3) ---------------------------------
__global__ void scam_prepack(const float* __restrict__ ln1g, const float* __restrict__ ln1b,
                             const float* __restrict__ ln2g, const float* __restrict__ ln2b,
                             const float* __restrict__ Wq, const float* __restrict__ Wk,
                             const float* __restrict__ Wv1, const float* __restrict__ Wv2,
                             unsigned short* __restrict__ WP, float* __restrict__ vecs) {
  __shared__ float Wkl[64][65];
  __shared__ float wqc[64][4];
  __shared__ float gb[4][64];
  const int tid = threadIdx.x;
  const int blk = blockIdx.x;
  const int c0 = blk * 4;
#pragma unroll
  for (int i = 0; i < 16; ++i) {
    int idx = i * 256 + tid;
    Wkl[idx >> 6][idx & 63] = Wk[idx];
  }
  { int o = tid >> 2, ci = tid & 3; wqc[o][ci] = Wq[o * 64 + c0 + ci]; }
  { int g = tid >> 6, e = tid & 63;
    const float* src = (g == 0) ? ln1g : (g == 1) ? ln1b : (g == 2) ? ln2g : ln2b;
    gb[g][e] = src[e]; }
  __syncthreads();
  const int ci = tid >> 6, cp = tid & 63;
  const int c = c0 + ci;
  float d = 0.f;
#pragma unroll 8
  for (int o = 0; o < 64; ++o) d += wqc[o][ci] * Wkl[o][cp];
  d *= LAM;
  float mb = gb[0][c] * d * gb[2][cp];
  float tb = gb[1][c] * d * gb[2][cp];
  atomicAdd(&vecs[cp], mb);
  atomicAdd(&vecs[64 + cp], tb);
  {
    unsigned short h, l; split2(mb, h, l);
    int nt = cp >> 4, l15 = cp & 15, ks = c >> 5, lg = (c >> 3) & 3, j = c & 7;
    int ui = (nt * 2 + ks) * 512 + (lg * 16 + l15) * 8 + j;
    WP[ui] = h; WP[4096 + ui] = l;
  }
  float t = d * gb[3][cp];
#pragma unroll
  for (int s = 1; s < 64; s <<= 1) t += __shfl_xor(t, s);
  if ((tid & 63) == 0) {
    vecs[128 + c] = gb[0][c] * t;
    atomicAdd(&vecs[192], gb[0][c] * t);
    atomicAdd(&vecs[193], gb[1][c] * t);
  }
  int idx2 = blk * 256 + tid;
#pragma unroll
  for (int m = 0; m < 2; ++m) {
    float v = (m ? Wv2 : Wv1)[idx2];
    unsigned short h, l; split2(v, h, l);
    int o = idx2 >> 6, cc = idx2 & 63;
    int mt = o >> 4, l15 = o & 15, ks = cc >> 5, lg = (cc >> 3) & 3, j = cc & 7;
    int ui = m * 8192 + (mt * 2 + ks) * 512 + (lg * 16 + l15) * 8 + j;
    WP[8192 + ui] = h;
    WP[8192 + ui + 4096] = l;
  }
}

// ---------------- main ------------------------------------------------------
struct SMem {
  unsigned short X[2][2][8704];        // [mat l/h][plane hi/lo][XSW(c,w)]  69,632 B
  union {
    unsigned short T2[2][9216];        // [plane][w*72+c']                  36,864 B
    unsigned short E[2][17408];        // [plane][XSW(wq,wk)]               69,632 B
    unsigned short O[2][2][9216];      // [O_h/O_l][plane][w*72+c]          73,728 B
  } R;
  float m_[2][128], r_[2][128];
  float uT[128], vT[128], zr[128], zc[128];
  float vT2[2][128], zrP[2][128], zcP[8][128];
  float s1v[64], t1v[64], mbv[64];
  float smbv, tmbv;
};

__launch_bounds__(1024, 1)
__global__ void scam_main(const float* __restrict__ xl_g, const float* __restrict__ xh_g,
                          const unsigned short* __restrict__ WP, const float* __restrict__ vecs,
                          float* __restrict__ out) {
  __shared__ __align__(16) SMem sm;
  const int tid = threadIdx.x;
  const int lane = tid & 63;
  const int wid = tid >> 6;
  const int stripe = wid >> 1, chalf = wid & 1;
  const int l15 = lane & 15, lg = lane >> 4;
  const int s = blockIdx.x;
  const size_t xoff = (size_t)(s >> 7) * 1048576u + (size_t)(s & 127) * 128u;

  // ---- load: issue global X reads first, then vecs, then split+store ----
  {
    const int q = tid & 31, cb = tid >> 5;   // cb 0..31, q*4 = w quad
    f32x4 v[4];
#pragma unroll
    for (int i = 0; i < 4; ++i) {
      int mat = i >> 1, c = cb + (i & 1) * 32;
      const float* xg = mat ? xh_g : xl_g;
      v[i] = *(const f32x4*)(xg + xoff + (size_t)c * 16384u + q * 4);
    }
    if (tid < 64) {
      sm.s1v[tid] = vecs[tid];
      sm.t1v[tid] = vecs[64 + tid];
      sm.mbv[tid] = vecs[128 + tid];
    }
    if (tid == 64) { sm.smbv = vecs[192]; sm.tmbv = vecs[193]; }
#pragma unroll
    for (int i = 0; i < 4; ++i) {
      int mat = i >> 1, c = cb + (i & 1) * 32;
      u16x4 h4, l4;
#pragma unroll
      for (int j = 0; j < 4; ++j) { unsigned short hh, ll; split2(v[i][j], hh, ll); h4[j] = hh; l4[j] = ll; }
      int idx = XSW(c, q * 4);
      *(u16x4*)&sm.X[mat][0][idx] = h4;
      *(u16x4*)&sm.X[mat][1][idx] = l4;
    }
  }
  __syncthreads();

  // ---- LN stats (+ xl . mbv for uT) ----
  {
    const int row = tid >> 2, qu = tid & 3;
    const int mat = row >> 7, w = row & 127;
    float a1 = 0.f, a2 = 0.f, a3 = 0.f;
#pragma unroll
    for (int i = 0; i < 16; ++i) {
      int c = qu * 16 + i;
      int idx = XSW(c, w);
      float x = comb(sm.X[mat][0][idx], sm.X[mat][1][idx]);
      a1 += x; a2 += x * x;
      if (mat == 0) a3 += x * sm.mbv[c];
    }
    a1 += __shfl_xor(a1, 1); a2 += __shfl_xor(a2, 1); a3 += __shfl_xor(a3, 1);
    a1 += __shfl_xor(a1, 2); a2 += __shfl_xor(a2, 2); a3 += __shfl_xor(a3, 2);
    if (qu == 0) {
      float mn = a1 * (1.f / 64.f);
      float var = fmaxf(a2 * (1.f / 64.f) - mn * mn, 0.f);
      float rs = rsqrtf(var + 1e-5f);
      sm.m_[mat][w] = mn; sm.r_[mat][w] = rs;
      if (mat == 0) sm.uT[w] = rs * (a3 - mn * sm.smbv) + sm.tmbv;
    }
  }
  __syncthreads();

  // ---- G1: T2 = LN1(xl) @ MB (LN in epilogue) ----
  {
    const int wA = stripe * 16 + l15;
    bf16x8 Ah[2], Al[2];
#pragma unroll
    for (int ks = 0; ks < 2; ++ks)
#pragma unroll
      for (int j = 0; j < 8; ++j) {
        int idx = XSW(ks * 32 + lg * 8 + j, wA);
        Ah[ks][j] = (short)sm.X[0][0][idx];
        Al[ks][j] = (short)sm.X[0][1][idx];
      }
    f32x4 acc[2];
#pragma unroll
    for (int nt = 0; nt < 2; ++nt)
#pragma unroll
      for (int r = 0; r < 4; ++r) acc[nt][r] = 0.f;
#pragma unroll
    for (int nt = 0; nt < 2; ++nt) {
      int ntg = chalf * 2 + nt;
#pragma unroll
      for (int ks = 0; ks < 2; ++ks) {
        const unsigned short* wp = WP + (ntg * 2 + ks) * 512 + lane * 8;
        bf16x8 Bh = *(const bf16x8*)wp;
        bf16x8 Bl = *(const bf16x8*)(wp + 4096);
        acc[nt] = mm3(Ah[ks], Al[ks], Bh, Bl, acc[nt]);
      }
    }
    float vsum[4] = {0.f, 0.f, 0.f, 0.f};
#pragma unroll
    for (int nt = 0; nt < 2; ++nt) {
      int cp = (chalf * 2 + nt) * 16 + l15;
      float sv = sm.s1v[cp], tv = sm.t1v[cp];
#pragma unroll
      for (int r = 0; r < 4; ++r) {
        int wr = stripe * 16 + lg * 4 + r;
        float t2 = sm.r_[0][wr] * (acc[nt][r] - sm.m_[0][wr] * sv) + tv;
        unsigned short h, l; split2(t2, h, l);
        sm.R.T2[0][wr * 72 + cp] = h;
        sm.R.T2[1][wr * 72 + cp] = l;
        vsum[r] += t2;
      }
    }
#pragma unroll
    for (int r = 0; r < 4; ++r) {
      float v = vsum[r];
      v += __shfl_xor(v, 1); v += __shfl_xor(v, 2);
      v += __shfl_xor(v, 4); v += __shfl_xor(v, 8);
      if (l15 == 0) sm.vT2[chalf][stripe * 16 + lg * 4 + r] = v;
    }
  }
  __syncthreads();

  // ---- G2: S2 = T2 @ xh^T -> E = exp2(S2) ----
  {
    if (tid < 128) sm.vT[tid] = sm.vT2[0][tid] + sm.vT2[1][tid];
    const int wA = stripe * 16 + l15;
    bf16x8 Ah[2], Al[2];
#pragma unroll
    for (int ks = 0; ks < 2; ++ks) {
      Ah[ks] = *(const bf16x8*)&sm.R.T2[0][wA * 72 + ks * 32 + lg * 8];
      Al[ks] = *(const bf16x8*)&sm.R.T2[1][wA * 72 + ks * 32 + lg * 8];
    }
    f32x4 acc[4];
#pragma unroll
    for (int nt = 0; nt < 4; ++nt)
#pragma unroll
      for (int r = 0; r < 4; ++r) acc[nt][r] = 0.f;
#pragma unroll
    for (int nt = 0; nt < 4; ++nt) {
      int wk = (chalf * 4 + nt) * 16 + l15;
#pragma unroll
      for (int ks = 0; ks < 2; ++ks) {
        bf16x8 Bh, Bl;
#pragma unroll
        for (int j = 0; j < 8; ++j) {
          int idx = XSW(ks * 32 + lg * 8 + j, wk);
          Bh[j] = (short)sm.X[1][0][idx];
          Bl[j] = (short)sm.X[1][1][idx];
        }
        acc[nt] = mm3(Ah[ks], Al[ks], Bh, Bl, acc[nt]);
      }
    }
    __syncthreads();   // T2 reads done; vT ready; E may overwrite T2
    float ev[4][4];
#pragma unroll
    for (int nt = 0; nt < 4; ++nt) {
      int wk = (chalf * 4 + nt) * 16 + l15;
      float rr = sm.r_[1][wk], mm = sm.m_[1][wk];
#pragma unroll
      for (int r = 0; r < 4; ++r) {
        int wq = stripe * 16 + lg * 4 + r;
        float s2 = rr * (acc[nt][r] - mm * sm.vT[wq]) + sm.uT[wq];
        float e = __builtin_amdgcn_exp2f(s2);
        ev[nt][r] = e;
        unsigned short h, l; split2(e, h, l);
        int idx = XSW(wq, wk);
        sm.R.E[0][idx] = h;
        sm.R.E[1][idx] = l;
      }
    }
#pragma unroll
    for (int r = 0; r < 4; ++r) {
      float v = ev[0][r] + ev[1][r] + ev[2][r] + ev[3][r];
      v += __shfl_xor(v, 1); v += __shfl_xor(v, 2);
      v += __shfl_xor(v, 4); v += __shfl_xor(v, 8);
      if (l15 == 0) sm.zrP[chalf][stripe * 16 + lg * 4 + r] = v;
    }
#pragma unroll
    for (int nt = 0; nt < 4; ++nt) {
      float v = ev[nt][0] + ev[nt][1] + ev[nt][2] + ev[nt][3];
      v += __shfl_xor(v, 16); v += __shfl_xor(v, 32);
      if (lg == 0) sm.zcP[stripe][(chalf * 4 + nt) * 16 + l15] = v;
    }
  }
  __syncthreads();

  // ---- PV: O_h = (E@Xh)*zr ; O_l = (E^T@Xl)*zc ----
  {
    if (tid < 128) {
      sm.zr[tid] = 1.0f / (sm.zrP[0][tid] + sm.zrP[1][tid]);
    } else if (tid < 256) {
      int c = tid - 128;
      float t = 0.f;
#pragma unroll
      for (int st = 0; st < 8; ++st) t += sm.zcP[st][c];
      sm.zc[c] = 1.0f / t;
    }
    const int wA = stripe * 16 + l15;
    f32x4 aH[2], aL[2];
#pragma unroll
    for (int nt = 0; nt < 2; ++nt)
#pragma unroll
      for (int r = 0; r < 4; ++r) { aH[nt][r] = 0.f; aL[nt][r] = 0.f; }
#pragma unroll
    for (int kt = 0; kt < 4; ++kt) {
      // E rows (A for O_h): b128 pair
      bf16x8 Eh = *(const bf16x8*)&sm.R.E[0][XSW(wA, kt * 32 + lg * 8)];
      bf16x8 El = *(const bf16x8*)&sm.R.E[1][XSW(wA, kt * 32 + lg * 8)];
      // E columns (A for O_l): u16 gather
      bf16x8 Th, Tl;
#pragma unroll
      for (int j = 0; j < 8; ++j) {
        int idx = XSW(kt * 32 + lg * 8 + j, wA);
        Th[j] = (short)sm.R.E[0][idx];
        Tl[j] = (short)sm.R.E[1][idx];
      }
#pragma unroll
      for (int nt = 0; nt < 2; ++nt) {
        int c = (chalf * 2 + nt) * 16 + l15;
        int bidx = XSW(c, kt * 32 + lg * 8);
        bf16x8 BHh = *(const bf16x8*)&sm.X[1][0][bidx];
        bf16x8 BHl = *(const bf16x8*)&sm.X[1][1][bidx];
        bf16x8 BLh = *(const bf16x8*)&sm.X[0][0][bidx];
        bf16x8 BLl = *(const bf16x8*)&sm.X[0][1][bidx];
        aH[nt] = mm3(Eh, El, BHh, BHl, aH[nt]);
        aL[nt] = mm3(Th, Tl, BLh, BLl, aL[nt]);
      }
    }
    __syncthreads();   // E reads done; zr/zc ready; O may overwrite E
#pragma unroll
    for (int nt = 0; nt < 2; ++nt) {
      int c = (chalf * 2 + nt) * 16 + l15;
#pragma unroll
      for (int r = 0; r < 4; ++r) {
        int w = stripe * 16 + lg * 4 + r;
        unsigned short h, l;
        split2(aH[nt][r] * sm.zr[w], h, l);
        sm.R.O[0][0][w * 72 + c] = h;
        sm.R.O[0][1][w * 72 + c] = l;
        split2(aL[nt][r] * sm.zc[w], h, l);
        sm.R.O[1][0][w * 72 + c] = h;
        sm.R.O[1][1][w * 72 + c] = l;
      }
    }
  }
  __syncthreads();

  // ---- P7: out_l^T = xl^T + Wv2@O_h^T ; out_h^T = xh^T + Wv1@O_l^T ----
  {
    const int mt = wid >> 2, np = wid & 3;
#pragma unroll
    for (int oi = 0; oi < 2; ++oi) {
      const int osel = oi;               // 0 -> O_h, 1 -> O_l
      const int wsel = oi ? 0 : 1;       // 0 -> Wv1, 1 -> Wv2
      const unsigned short* WA = WP + 8192 + wsel * 8192;
      bf16x8 Ah[2], Al[2];
#pragma unroll
      for (int ks = 0; ks < 2; ++ks) {
        const unsigned short* wp = WA + (mt * 2 + ks) * 512 + lane * 8;
        Ah[ks] = *(const bf16x8*)wp;
        Al[ks] = *(const bf16x8*)(wp + 4096);
      }
      f32x4 acc[2];
#pragma unroll
      for (int nt2 = 0; nt2 < 2; ++nt2)
#pragma unroll
        for (int r = 0; r < 4; ++r) acc[nt2][r] = 0.f;
#pragma unroll
      for (int nt2 = 0; nt2 < 2; ++nt2) {
        int wc = (np * 2 + nt2) * 16 + l15;
#pragma unroll
        for (int ks = 0; ks < 2; ++ks) {
          bf16x8 Bh = *(const bf16x8*)&sm.R.O[osel][0][wc * 72 + ks * 32 + lg * 8];
          bf16x8 Bl = *(const bf16x8*)&sm.R.O[osel][1][wc * 72 + ks * 32 + lg * 8];
          acc[nt2] = mm3(Ah[ks], Al[ks], Bh, Bl, acc[nt2]);
        }
      }
      const float* res = (oi ? xh_g : xl_g) + xoff;
      float* og = out + (size_t)oi * 16777216u + xoff;
#pragma unroll
      for (int nt2 = 0; nt2 < 2; ++nt2) {
        int wc = (np * 2 + nt2) * 16 + l15;
#pragma unroll
        for (int r = 0; r < 4; ++r) {
          int o = mt * 16 + lg * 4 + r;
          size_t a = (size_t)o * 16384u + wc;
          og[a] = acc[nt2][r] + res[a];
        }
      }
    }
  }
}

extern "C" void kernel_launch(void* const* d_in, const int* in_sizes, int n_in,
                              void* d_out, int out_size, void* d_ws, size_t ws_size,
                              hipStream_t stream) {
  (void)in_sizes; (void)n_in; (void)out_size; (void)ws_size;
  unsigned short* WP = (unsigned short*)d_ws;            // 48 KiB frag planes
  float* vecs = (float*)((char*)d_ws + 49152);           // 256 floats
  hipMemsetAsync(vecs, 0, 1024, stream);
  scam_prepack<<<16, 256, 0, stream>>>(
      (const float*)d_in[2], (const float*)d_in[3],
      (const float*)d_in[4], (const float*)d_in[5],
      (const float*)d_in[6], (const float*)d_in[7],
      (const float*)d_in[8], (const float*)d_in[9], WP, vecs);
  scam_main<<<2048, 1024, 0, stream>>>(
      (const float*)d_in[0], (const float*)d_in[1], WP, vecs, (float*)d_out);
}